// Round 15
// baseline (34.723 us; speedup 1.0000x reference)
//
#include <hip/hip_runtime.h>

// D-FINE post-processor, SINGLE fused kernel: one block per batch (256 x 1024).
//   Filter (R10 structure): three burst phases (7+7+6 float4/thread, loads
//     issued before a sched_barrier, then consumed). NEW: wave-uniform BALLOT
//     compaction -- per component, hit = in-bounds && (x > THR); __ballot;
//     scalar skip if zero; ONE LDS atomicAdd per wave per non-empty mask
//     (leader lane), popc-prefix lane offsets. No per-lane divergent atomics.
//     {x > THR} is a prefix of the descending order, so if K <= n <= CAPL the
//     top-K is provably contained in cand[].
//   Select (R14): grouped rank-based selection (thread ranks 2 candidates
//     against the broadcast j-stream), exact jax.lax.top_k tie semantics via
//     packed (key<<32)|~idx keys. Scatter-emit by rank.
//   Fallback: exact in-kernel 4096-bin histogram selection if the bound check
//     fails (any input distribution stays correct).
// Output (float32): labels [B*K] | boxes [B*K*4] | scores [B*K]

constexpr int   NT    = 1024;
constexpr int   NBINS = 4096;
constexpr int   CAPL  = 4096;   // LDS candidate capacity
constexpr float THR   = 2.5f;   // static pre-filter: ~497 hits/batch expected

__device__ __forceinline__ unsigned f2key(float f) {
    unsigned u = __float_as_uint(f);
    return (u & 0x80000000u) ? ~u : (u | 0x80000000u);
}
__device__ __forceinline__ float key2f(unsigned k) {
    unsigned u = (k & 0x80000000u) ? (k & 0x7FFFFFFFu) : ~k;
    return __uint_as_float(u);
}
__device__ __forceinline__ unsigned long long packkv(unsigned key, unsigned idx) {
    return ((unsigned long long)key << 32) | (unsigned long long)(0xFFFFFFFFu - idx);
}

// wave-uniform compaction: one LDS atomic per wave per non-empty ballot
__device__ __forceinline__ void consume_ballot(
    float x, bool inb, unsigned idx, unsigned* lcnt, unsigned long long* cand, int lane)
{
    bool hit = inb && (x > THR);
    unsigned long long mask = __ballot(hit);
    if (mask != 0ull) {                                   // scalar-uniform branch
        int leader = __ffsll((unsigned long long)mask) - 1;
        unsigned base = 0u;
        if (lane == leader) base = atomicAdd(lcnt, (unsigned)__popcll(mask));
        base = (unsigned)__shfl((int)base, leader);
        if (hit) {
            unsigned off = (unsigned)__popcll(mask & ((1ull << lane) - 1ull));
            unsigned p = base + off;
            if (p < (unsigned)CAPL) cand[p] = packkv(f2key(x), idx);
        }
    }
}

__device__ __forceinline__ void consume4_ballot(
    float4 v, int i4, int N4, unsigned* lcnt, unsigned long long* cand, int lane)
{
    bool inb = (i4 < N4);
    unsigned bi = (unsigned)(4 * i4);
    consume_ballot(v.x, inb, bi + 0, lcnt, cand, lane);
    consume_ballot(v.y, inb, bi + 1, lcnt, cand, lane);
    consume_ballot(v.z, inb, bi + 2, lcnt, cand, lane);
    consume_ballot(v.w, inb, bi + 3, lcnt, cand, lane);
}

template<int UNROLL>
__device__ __forceinline__ void filter_phase(
    const float4* __restrict__ base4, int start, int N4,
    unsigned* lcnt, unsigned long long* cand, int tid, int lane)
{
    float4 v[UNROLL];
    #pragma unroll
    for (int j = 0; j < UNROLL; ++j) {
        int i4 = start + j * NT + tid;
        int c  = (i4 < N4) ? i4 : (N4 - 1);          // clamped load, predicated use
        v[j] = base4[c];
    }
    __builtin_amdgcn_sched_barrier(0);               // all UNROLL loads in flight
    #pragma unroll
    for (int j = 0; j < UNROLL; ++j) {
        int i4 = start + j * NT + tid;
        consume4_ballot(v[j], i4, N4, lcnt, cand, lane);
    }
}

__global__ __launch_bounds__(NT) void dfine_fused_kernel(
    const float* __restrict__ logits,   // [B, Q*C]
    const float* __restrict__ pboxes,   // [B, Q, 4]  (cx, cy, w, h)
    const float* __restrict__ sizes,    // [B, 2]
    float* __restrict__ out,            // labels | boxes | scores
    int B, int Q, int C, int K)
{
    const int b    = blockIdx.x;
    const int tid  = threadIdx.x;
    const int lane = tid & 63;
    const int N    = Q * C;
    const int N4   = N >> 2;            // N divisible by 4 (C=80)
    const float4* __restrict__ base4 = reinterpret_cast<const float4*>(logits + (long long)b * N);

    __shared__ unsigned long long cand[CAPL];   // 32 KB
    __shared__ unsigned hist[NBINS];            // 16 KB (fallback only)
    __shared__ unsigned partial[NT];            //  4 KB (fallback only)
    __shared__ unsigned lcnt;
    __shared__ unsigned candCount;
    __shared__ unsigned threshBin;

    if (tid == 0) lcnt = 0u;
    __syncthreads();

    // ---- filter: three burst phases (cover N4 <= 20*NT) ----
    filter_phase<7>(base4, 0,       N4, &lcnt, cand, tid, lane);
    filter_phase<7>(base4, 7 * NT,  N4, &lcnt, cand, tid, lane);
    filter_phase<6>(base4, 14 * NT, N4, &lcnt, cand, tid, lane);
    // generic tail for hypothetical larger shapes (no-op at N4 = 20000)
    for (int i4 = 20 * NT + tid; i4 < N4; i4 += NT) {
        float4 x = base4[i4];
        float mx = fmaxf(fmaxf(x.x, x.y), fmaxf(x.z, x.w));
        if (mx > THR) {
            unsigned bi = (unsigned)(4 * i4);
            if (x.x > THR) { unsigned p = atomicAdd(&lcnt, 1u);
                if (p < (unsigned)CAPL) cand[p] = packkv(f2key(x.x), bi + 0); }
            if (x.y > THR) { unsigned p = atomicAdd(&lcnt, 1u);
                if (p < (unsigned)CAPL) cand[p] = packkv(f2key(x.y), bi + 1); }
            if (x.z > THR) { unsigned p = atomicAdd(&lcnt, 1u);
                if (p < (unsigned)CAPL) cand[p] = packkv(f2key(x.z), bi + 2); }
            if (x.w > THR) { unsigned p = atomicAdd(&lcnt, 1u);
                if (p < (unsigned)CAPL) cand[p] = packkv(f2key(x.w), bi + 3); }
        }
    }
    __syncthreads();

    int n;
    const unsigned tot = lcnt;
    if (tot >= (unsigned)K && tot <= (unsigned)CAPL) {
        n = (int)tot;                               // hot path: cand[] already in LDS
    } else {
        // ---- fallback: exact histogram selection over the full batch ----
        const float* __restrict__ lg = logits + (long long)b * N;
        for (int i = tid; i < NBINS; i += NT) hist[i] = 0u;
        if (tid == 0) candCount = 0u;
        __syncthreads();
        for (int i = tid; i < N; i += NT)
            atomicAdd(&hist[f2key(lg[i]) >> 20], 1u);
        __syncthreads();
        {
            const int BPT = NBINS / NT;
            unsigned s = 0;
            #pragma unroll
            for (int m = 0; m < BPT; ++m) s += hist[tid * BPT + m];
            partial[tid] = s;
        }
        __syncthreads();
        if (tid < 64) {
            const int PPG = NT / 64;
            unsigned gs = 0;
            #pragma unroll
            for (int m = 0; m < PPG; ++m) gs += partial[tid * PPG + m];
            unsigned pre = gs;
            #pragma unroll
            for (int off = 1; off < 64; off <<= 1) {
                unsigned t = __shfl_up(pre, off);
                if (tid >= off) pre += t;
            }
            unsigned total = __shfl(pre, 63);
            unsigned suf   = total - (pre - gs);
            unsigned long long m1 = __ballot(suf >= (unsigned)K);
            int g = 63 - __clzll(m1);
            unsigned above = total - __shfl(pre, g);
            unsigned hv = hist[g * 64 + tid];
            unsigned pre2 = hv;
            #pragma unroll
            for (int off = 1; off < 64; off <<= 1) {
                unsigned t = __shfl_up(pre2, off);
                if (tid >= off) pre2 += t;
            }
            unsigned total2 = __shfl(pre2, 63);
            unsigned suf2   = above + total2 - (pre2 - hv);
            unsigned long long m2 = __ballot(suf2 >= (unsigned)K);
            int l2 = 63 - __clzll(m2);
            if (tid == 0) threshBin = (unsigned)(g * 64 + l2);
        }
        __syncthreads();
        const unsigned tb = threshBin;
        for (int i = tid; i < N; i += NT) {
            unsigned k = f2key(lg[i]);
            if ((k >> 20) >= tb) {
                unsigned p = atomicAdd(&candCount, 1u);
                if (p < (unsigned)CAPL) cand[p] = packkv(k, (unsigned)i);
            }
        }
        __syncthreads();
        n = (int)min(candCount, (unsigned)CAPL);
    }

    // ---- grouped rank-based selection + emit (thread ranks 2t, 2t+1) ----
    const int BK = B * K;
    float* __restrict__ out_labels = out;
    float* __restrict__ out_boxes  = out + BK;
    float* __restrict__ out_scores = out + (long long)BK * 5;
    const float s0 = sizes[2 * b];
    const float s1 = sizes[2 * b + 1];

    for (int base = 0; base < n; base += 2 * NT) {
        int t0 = base + 2 * tid;
        if (t0 >= n) break;
        unsigned long long my0 = cand[t0];
        bool has1 = (t0 + 1) < n;
        unsigned long long my1 = has1 ? cand[t0 + 1] : 0ull;
        int r0 = 0, r1 = 0;
        for (int j = 0; j < n; ++j) {
            unsigned long long c = cand[j];       // broadcast read serves both ranks
            r0 += (c > my0);
            r1 += (c > my1);
        }
        #pragma unroll
        for (int g = 0; g < 2; ++g) {
            unsigned long long my = g ? my1 : my0;
            int r = g ? r1 : r0;
            if ((g == 0 || has1) && r < K) {
                unsigned key = (unsigned)(my >> 32);
                unsigned idx = 0xFFFFFFFFu - (unsigned)(my & 0xFFFFFFFFull);
                float logit = key2f(key);
                float score = 1.0f / (1.0f + expf(-logit));
                int label = (int)(idx % (unsigned)C);
                int q     = (int)(idx / (unsigned)C);
                float4 bp = *reinterpret_cast<const float4*>(pboxes + ((long long)b * Q + q) * 4);
                int o = b * K + r;
                out_labels[o] = (float)label;
                out_scores[o] = score;
                float4 bb;
                bb.x = (bp.x - 0.5f * bp.z) * s0;
                bb.y = (bp.y - 0.5f * bp.w) * s1;
                bb.z = (bp.x + 0.5f * bp.z) * s0;
                bb.w = (bp.y + 0.5f * bp.w) * s1;
                *reinterpret_cast<float4*>(out_boxes + 4LL * o) = bb;
            }
        }
    }
}

extern "C" void kernel_launch(void* const* d_in, const int* in_sizes, int n_in,
                              void* d_out, int out_size, void* d_ws, size_t ws_size,
                              hipStream_t stream) {
    const float* logits = (const float*)d_in[0];
    const float* pboxes = (const float*)d_in[1];
    const float* sizes  = (const float*)d_in[2];

    const int B = in_sizes[2] / 2;                 // 256
    const int Q = in_sizes[1] / (4 * B);           // 1000
    const int C = in_sizes[0] / (B * Q);           // 80
    const int K = out_size / (6 * B);              // 300

    dfine_fused_kernel<<<B, NT, 0, stream>>>(
        logits, pboxes, sizes, (float*)d_out, B, Q, C, K);
}